// Round 8
// baseline (455.502 us; speedup 1.0000x reference)
//
#include <hip/hip_runtime.h>

#define D_DIM 1024
#define N_INNER 4096
#define NEXP 8
#define T_TOK 8192
#define EPSV 1e-6f

typedef __attribute__((ext_vector_type(4))) float f32x4;
typedef __bf16 bf16x8 __attribute__((ext_vector_type(8)));

typedef const __attribute__((address_space(1))) void gvoid_t;
typedef __attribute__((address_space(3))) void lvoid_t;

#define VMCNT(n) asm volatile("s_waitcnt vmcnt(" #n ")" ::: "memory")
#define SCHEDB() __builtin_amdgcn_sched_barrier(0)

static __device__ __forceinline__ unsigned short f2bf(float f) {
    unsigned int u = __float_as_uint(f);
    u = u + 0x7fffu + ((u >> 16) & 1u);   // round-to-nearest-even
    return (unsigned short)(u >> 16);
}

// ---------------- gating: one wave per token ----------------
__global__ __launch_bounds__(256) void k_gate(const float* __restrict__ x,
                                              const float* __restrict__ Wg,
                                              const float* __restrict__ bg,
                                              int* __restrict__ top1,
                                              float* __restrict__ score) {
    __shared__ float wgT[NEXP * D_DIM];
    int tid = threadIdx.x;
    for (int i = tid; i < NEXP * D_DIM; i += 256)
        wgT[(i & 7) * D_DIM + (i >> 3)] = Wg[i];
    __syncthreads();

    int wid = tid >> 6, lane = tid & 63;
    int t = blockIdx.x * 4 + wid;
    float acc[8] = {0.f, 0.f, 0.f, 0.f, 0.f, 0.f, 0.f, 0.f};
    const float* xp = x + (size_t)t * D_DIM + lane;
    for (int c = 0; c < D_DIM / 64; ++c) {
        float xv = xp[c * 64];
#pragma unroll
        for (int e = 0; e < 8; ++e) acc[e] += xv * wgT[e * D_DIM + c * 64 + lane];
    }
#pragma unroll
    for (int e = 0; e < 8; ++e) {
        float v = acc[e];
        for (int o = 32; o; o >>= 1) v += __shfl_xor(v, o);
        acc[e] = v;
    }
    if (lane == 0) {
        float mx = -1e30f;
#pragma unroll
        for (int e = 0; e < 8; ++e) { acc[e] += bg[e]; mx = fmaxf(mx, acc[e]); }
        float p[8], s = 0.f;
#pragma unroll
        for (int e = 0; e < 8; ++e) { p[e] = expf(acc[e] - mx); s += p[e]; }
        int best = 0; float bv = acc[0];
#pragma unroll
        for (int e = 1; e < 8; ++e) if (acc[e] > bv) { bv = acc[e]; best = e; }
        top1[t]  = best;
        score[t] = p[best] / s;
    }
}

// ---------------- deterministic per-expert reduce + BM=256 tile table + cursors ----------------
__global__ void k_meta(const int* __restrict__ top1, const float* __restrict__ score,
                       int* __restrict__ mi, float* __restrict__ mf) {
    int wid = threadIdx.x >> 6, lane = threadIdx.x & 63;
    float s[8] = {0.f, 0.f, 0.f, 0.f, 0.f, 0.f, 0.f, 0.f};
    int   c[8] = {0, 0, 0, 0, 0, 0, 0, 0};
    for (int it = 0; it < T_TOK / 512; ++it) {
        int t = wid * (T_TOK / 8) + it * 64 + lane;
        int e = top1[t]; float sc = score[t];
#pragma unroll
        for (int k = 0; k < 8; ++k) {
            bool m = (e == k);
            s[k] += m ? sc : 0.f;
            c[k] += m ? 1 : 0;
        }
    }
#pragma unroll
    for (int k = 0; k < 8; ++k)
        for (int o = 32; o; o >>= 1) { s[k] += __shfl_down(s[k], o); c[k] += __shfl_down(c[k], o); }
    __shared__ float ss[8][8];
    __shared__ int   cc[8][8];
    if (lane == 0) {
#pragma unroll
        for (int k = 0; k < 8; ++k) { ss[wid][k] = s[k]; cc[wid][k] = c[k]; }
    }
    __syncthreads();
    if (threadIdx.x == 0) {
        int off = 0, ntA = 0;
        for (int e = 0; e < 8; ++e) {
            int   ct = 0; float st = 0.f;
#pragma unroll
            for (int w2 = 0; w2 < 8; ++w2) { ct += cc[w2][e]; st += ss[w2][e]; }
            mi[16 + e] = off;                       // scatter cursor
            mf[e]      = st;
            mf[8 + e]  = (float)T_TOK / (st + EPSV);
            int end = off + ct;
            for (int m = off; m < end; m += 256) {  // BM=256 tiles (expert-sorted order)
                mi[64  + ntA] = e;
                mi[104 + ntA] = m;
                mi[144 + ntA] = end;
                ntA++;
            }
            off = end;
        }
        mi[0] = ntA;
#pragma unroll
        for (int i = 0; i < 16; ++i) mi[32 + i] = 0;   // per-XCD steal cursors (2 banks of 8)
    }
}

// ---------------- scatter tokens to expert-contiguous slots ----------------
__global__ __launch_bounds__(256) void k_scatter(const int* __restrict__ top1,
                                                 const float* __restrict__ score,
                                                 int* __restrict__ mi,
                                                 const float* __restrict__ mf,
                                                 int* __restrict__ perm,
                                                 float* __restrict__ coef) {
    int t = blockIdx.x * 256 + threadIdx.x;
    if (t >= T_TOK) return;
    int e = top1[t];
    int slot = atomicAdd(&mi[16 + e], 1);
    perm[slot] = t;
    coef[slot] = score[t] * mf[8 + e];
}

// ---------------- gather x rows into bf16, slot order ----------------
__global__ __launch_bounds__(256) void k_gatherX(const float* __restrict__ x,
                                                 const int* __restrict__ perm,
                                                 unsigned short* __restrict__ Xg) {
    int i = blockIdx.x * 256 + threadIdx.x;
    int slot = i >> 7, ch = (i & 127) * 8;
    int t = perm[slot];
    const float4* px = (const float4*)(x + (size_t)t * D_DIM + ch);
    float4 a = px[0], b = px[1];
    union { unsigned short u[8]; uint4 v; } o;
    o.u[0] = f2bf(a.x); o.u[1] = f2bf(a.y); o.u[2] = f2bf(a.z); o.u[3] = f2bf(a.w);
    o.u[4] = f2bf(b.x); o.u[5] = f2bf(b.y); o.u[6] = f2bf(b.z); o.u[7] = f2bf(b.w);
    *(uint4*)(Xg + (size_t)slot * D_DIM + ch) = o.v;
}

// ---------------- transpose + cast weights: [E][R][C] f32 -> [E][C][R] bf16 ----------------
__global__ __launch_bounds__(256) void k_transp(const float* __restrict__ W,
                                                unsigned short* __restrict__ Wt,
                                                int R, int C) {
    __shared__ float tile[64][65];
    int e  = blockIdx.z;
    int c0 = blockIdx.x * 64, r0 = blockIdx.y * 64;
    int tr = threadIdx.x >> 6, tc = threadIdx.x & 63;
    const float* Win = W + ((size_t)e * R + r0) * C + c0;
#pragma unroll
    for (int it = 0; it < 16; ++it) {
        int r = it * 4 + tr;
        tile[r][tc] = Win[(size_t)r * C + tc];
    }
    __syncthreads();
    unsigned short* Wo = Wt + ((size_t)e * C + c0) * R + r0;
#pragma unroll
    for (int it = 0; it < 16; ++it) {
        int r = it * 4 + tr;
        Wo[(size_t)r * R + tc] = f2bf(tile[tc][r]);
    }
}

// ============ PERSISTENT grouped GEMM, 8-phase 256x256, NT=16, per-XCD L2-sized queues ============
// Grid 256 (1 block/CU).  xcd = bid&7 (HW round-robin).  Each XCD owns a private queue of
// nt*2 entries, ti-major (expert-grouped since slots are expert-sorted):
//   MODE 0 (H=relu(Xg@W1t), K=1024):  q -> (ti=q>>1, n0=(xcd*2+(q&1))*256)
//     per-XCD working set: B = 1 expert x 512 cols x 1024 k = 1 MB (L2-resident, ~9x reuse)
//   MODE 1 (out+=coef*(H@W2t), K=4096 split-K 4): g = xcd*2+(q&1) in [0,16);
//     n0=(g>>2)*256, ktB=(g&3)*16  -> per-XCD B slice = 1 MB; 4 commutative f32 atomic adds/out.
template <int MODE>
__global__ __launch_bounds__(512, 2) void k_moe_gemm(const unsigned short* __restrict__ A,
                                                     const unsigned short* __restrict__ B,
                                                     void* __restrict__ Cout,
                                                     int* __restrict__ mi,
                                                     const int* __restrict__ perm,
                                                     const float* __restrict__ coef,
                                                     const int KSTRIDE, const int N_TOT) {
    extern __shared__ __align__(16) char lds[];
    __shared__ int sh_t;
    constexpr int NT = 16;
    const int nt     = mi[0];
    const int totalq = nt * 2;
    const int xcd    = blockIdx.x & 7;
    int* ctr = &mi[32 + MODE * 8 + xcd];

    const int tid = threadIdx.x;
    const int w   = tid >> 6, l = tid & 63;
    const int wr  = w >> 2, wc = w & 3;
    const int fr  = l & 15, fq = l >> 4;
    const int gch = (l & 7) ^ (l >> 3);        // inverse-swizzled 16B chunk for staging
    const int rTb = w * 8 + (l >> 3);          // staging row within 64-row half-stage

    for (;;) {
        if (tid == 0) sh_t = atomicAdd(ctr, 1);
        __syncthreads();
        const int q = sh_t;
        if (q >= totalq) break;

        int ti = q >> 1, n0, ktB;
        if (MODE == 0) { n0 = ((xcd << 1) + (q & 1)) << 8; ktB = 0; }
        else           { int g = (xcd << 1) + (q & 1); n0 = (g >> 2) << 8; ktB = (g & 3) * 16; }
        const int e    = mi[64 + ti];
        const int m0   = mi[104 + ti];
        const int mend = mi[144 + ti];
        const unsigned short* Bexp = B + (size_t)e * N_TOT * KSTRIDE;

        const unsigned short* aP[2][2];
        const unsigned short* bP[2][2];
#pragma unroll
        for (int h = 0; h < 2; ++h)
#pragma unroll
            for (int s = 0; s < 2; ++s) {
                int rT = h * 128 + s * 64 + rTb;
                int rG = m0 + rT; if (rG > T_TOK - 1) rG = T_TOK - 1;   // clamp tail rows
                aP[h][s] = A + (size_t)rG * KSTRIDE + (size_t)ktB * 64 + gch * 8;
                bP[h][s] = Bexp + (size_t)(n0 + rT) * KSTRIDE + (size_t)ktB * 64 + gch * 8;
            }

        auto stA = [&](int kt, int h) {
            if (kt < NT) {
                char* d = lds + (kt & 1) * 65536 + h * 16384 + w * 1024;
#pragma unroll
                for (int s = 0; s < 2; ++s)
                    __builtin_amdgcn_global_load_lds((gvoid_t*)(aP[h][s] + kt * 64),
                                                     (lvoid_t*)(d + s * 8192), 16, 0, 0);
            }
        };
        auto stB = [&](int kt, int h) {
            if (kt < NT) {
                char* d = lds + (kt & 1) * 65536 + 32768 + h * 16384 + w * 1024;
#pragma unroll
                for (int s = 0; s < 2; ++s)
                    __builtin_amdgcn_global_load_lds((gvoid_t*)(bP[h][s] + kt * 64),
                                                     (lvoid_t*)(d + s * 8192), 16, 0, 0);
            }
        };

        f32x4 acc[8][4];
#pragma unroll
        for (int m = 0; m < 8; ++m)
#pragma unroll
            for (int n = 0; n < 4; ++n) acc[m][n] = (f32x4){0.f, 0.f, 0.f, 0.f};

        // prologue: tile0 (A+B) + tile1 B -> 12 loads; vmcnt(4) completes tile0
        stA(0, 0); stA(0, 1); stB(0, 0); stB(0, 1); stB(1, 0); stB(1, 1);
        VMCNT(4);
        SCHEDB();
        __builtin_amdgcn_s_barrier();

        constexpr int NITER = NT >> 1;
        for (int jj = 0; jj < NITER; ++jj) {
            const int t0 = 2 * jj;
#pragma unroll
            for (int hv = 0; hv < 2; ++hv) {
                const int tcur = t0 + hv;
                const char* buf = lds + (tcur & 1) * 65536;
                bf16x8 bfr[4][2];
#pragma unroll
                for (int qq = 0; qq < 4; ++qq) {
                    if (qq == 0) {
#pragma unroll
                        for (int n = 0; n < 4; ++n)
#pragma unroll
                            for (int ks = 0; ks < 2; ++ks) {
                                int row = wc * 64 + n * 16 + fr;
                                bfr[n][ks] = *(const bf16x8*)(buf + 32768 + row * 128 +
                                                              (((ks * 4 + fq) ^ (fr & 7)) << 4));
                            }
                    }
                    bf16x8 afr[2][2];
#pragma unroll
                    for (int mm = 0; mm < 2; ++mm)
#pragma unroll
                        for (int ks = 0; ks < 2; ++ks) {
                            int row = wr * 128 + (2 * qq + mm) * 16 + fr;
                            afr[mm][ks] = *(const bf16x8*)(buf + row * 128 +
                                                           (((ks * 4 + fq) ^ (fr & 7)) << 4));
                        }
                    if (hv == 0) {
                        if (qq == 0)      { stA(t0 + 1, 0); }
                        else if (qq == 1) { stA(t0 + 1, 1); stB(t0 + 2, 0); }
                        else if (qq == 2) { stB(t0 + 2, 1); }
                    } else {
                        if (qq == 0)      { stA(t0 + 2, 0); }
                        else if (qq == 1) { stA(t0 + 2, 1); stB(t0 + 3, 0); }
                        else if (qq == 2) { stB(t0 + 3, 1); }
                    }
                    SCHEDB();
                    __builtin_amdgcn_s_barrier();
                    asm volatile("s_waitcnt lgkmcnt(0)" ::: "memory");
                    SCHEDB();
                    __builtin_amdgcn_s_setprio(1);
#pragma unroll
                    for (int mm = 0; mm < 2; ++mm)
#pragma unroll
                        for (int n = 0; n < 4; ++n)
#pragma unroll
                            for (int ks = 0; ks < 2; ++ks)
                                acc[2 * qq + mm][n] = __builtin_amdgcn_mfma_f32_16x16x32_bf16(
                                    afr[mm][ks], bfr[n][ks], acc[2 * qq + mm][n], 0, 0, 0);
                    __builtin_amdgcn_s_setprio(0);
                    SCHEDB();
                    if (qq == 3) {
                        if (jj == NITER - 1) { VMCNT(0); } else { VMCNT(4); }
                    }
                    __builtin_amdgcn_s_barrier();
                }
            }
        }

        // ---- epilogue (no LDS use; stores drain while next tile stages) ----
        if (MODE == 0) {
            unsigned short* H = (unsigned short*)Cout;
#pragma unroll
            for (int m = 0; m < 8; ++m) {
                int rb = m0 + wr * 128 + m * 16 + fq * 4;
#pragma unroll
                for (int r = 0; r < 4; ++r) {
                    int row = rb + r;
                    if (row < mend) {
#pragma unroll
                        for (int n = 0; n < 4; ++n) {
                            int col = n0 + wc * 64 + n * 16 + fr;
                            float v = fmaxf(acc[m][n][r], 0.f);
                            H[(size_t)row * N_TOT + col] = f2bf(v);
                        }
                    }
                }
            }
        } else {
            float* O = (float*)Cout;
#pragma unroll
            for (int m = 0; m < 8; ++m) {
                int rb = m0 + wr * 128 + m * 16 + fq * 4;
#pragma unroll
                for (int r = 0; r < 4; ++r) {
                    int row = rb + r;
                    if (row < mend) {
                        int   tkn = perm[row];
                        float cf  = coef[row];
#pragma unroll
                        for (int n = 0; n < 4; ++n) {
                            int col = n0 + wc * 64 + n * 16 + fr;
                            unsafeAtomicAdd(&O[(size_t)tkn * N_TOT + col], cf * acc[m][n][r]);
                        }
                    }
                }
            }
        }
    }
}

extern "C" void kernel_launch(void* const* d_in, const int* in_sizes, int n_in,
                              void* d_out, int out_size, void* d_ws, size_t ws_size,
                              hipStream_t stream) {
    const float* x  = (const float*)d_in[0];
    const float* Wg = (const float*)d_in[1];
    const float* bg = (const float*)d_in[2];
    const float* W1 = (const float*)d_in[3];
    const float* W2 = (const float*)d_in[4];

    char* ws = (char*)d_ws;
    int*   mi    = (int*)ws;
    float* mf    = (float*)(ws + 2048);
    int*   top1  = (int*)(ws + 4096);
    float* score = (float*)(ws + 36864);
    int*   perm  = (int*)(ws + 69632);
    float* coef  = (float*)(ws + 102400);
    unsigned short* Xg = (unsigned short*)(ws + 135168);     // 8192 x 1024 bf16
    unsigned short* H  = (unsigned short*)(ws + 16912384);   // 8192 x 4096 bf16
    unsigned short* Wt = (unsigned short*)(ws + 84021248);   // 8 x 4096 x 1024 bf16 (shared)

    hipFuncSetAttribute((const void*)&k_moe_gemm<0>,
                        hipFuncAttributeMaxDynamicSharedMemorySize, 131072);
    hipFuncSetAttribute((const void*)&k_moe_gemm<1>,
                        hipFuncAttributeMaxDynamicSharedMemorySize, 131072);

    // zero d_out: GEMM2 combines split-K quarters with commutative f32 atomic adds
    hipMemsetAsync(d_out, 0, (size_t)out_size * sizeof(float), stream);

    k_gate<<<dim3(T_TOK / 4), dim3(256), 0, stream>>>(x, Wg, bg, top1, score);
    k_meta<<<dim3(1), dim3(512), 0, stream>>>(top1, score, mi, mf);
    k_scatter<<<dim3(T_TOK / 256), dim3(256), 0, stream>>>(top1, score, mi, mf, perm, coef);
    k_gatherX<<<dim3(T_TOK * 128 / 256), dim3(256), 0, stream>>>(x, perm, Xg);

    // W1: [8][1024][4096] f32 -> Wt [8][4096][1024] bf16
    k_transp<<<dim3(N_INNER / 64, D_DIM / 64, NEXP), dim3(256), 0, stream>>>(W1, Wt, D_DIM, N_INNER);
    // H = relu(Xg @ W1t): persistent, per-XCD queues (nt*2 entries each), NT=16
    k_moe_gemm<0><<<dim3(256), dim3(512), 131072, stream>>>(
        Xg, Wt, (void*)H, mi, perm, coef, D_DIM, N_INNER);
    // W2: [8][4096][1024] f32 -> Wt [8][1024][4096] bf16
    k_transp<<<dim3(D_DIM / 64, N_INNER / 64, NEXP), dim3(256), 0, stream>>>(W2, Wt, N_INNER, D_DIM);
    // out += coef * (H @ W2t): persistent, split-K 4, per-XCD queues (nt*2 entries), NT=16
    k_moe_gemm<1><<<dim3(256), dim3(512), 131072, stream>>>(
        H, Wt, d_out, mi, perm, coef, N_INNER, D_DIM);
}

// Round 9
// 435.675 us; speedup vs baseline: 1.0455x; 1.0455x over previous
//
#include <hip/hip_runtime.h>

#define D_DIM 1024
#define N_INNER 4096
#define NEXP 8
#define T_TOK 8192
#define EPSV 1e-6f

typedef __attribute__((ext_vector_type(4))) float f32x4;
typedef __bf16 bf16x8 __attribute__((ext_vector_type(8)));

typedef const __attribute__((address_space(1))) void gvoid_t;
typedef __attribute__((address_space(3))) void lvoid_t;

#define VMCNT(n) asm volatile("s_waitcnt vmcnt(" #n ")" ::: "memory")
#define SCHEDB() __builtin_amdgcn_sched_barrier(0)

static __device__ __forceinline__ unsigned short f2bf(float f) {
    unsigned int u = __float_as_uint(f);
    u = u + 0x7fffu + ((u >> 16) & 1u);   // round-to-nearest-even
    return (unsigned short)(u >> 16);
}

// ---------------- gating: one wave per token ----------------
__global__ __launch_bounds__(256) void k_gate(const float* __restrict__ x,
                                              const float* __restrict__ Wg,
                                              const float* __restrict__ bg,
                                              int* __restrict__ top1,
                                              float* __restrict__ score) {
    __shared__ float wgT[NEXP * D_DIM];
    int tid = threadIdx.x;
    for (int i = tid; i < NEXP * D_DIM; i += 256)
        wgT[(i & 7) * D_DIM + (i >> 3)] = Wg[i];
    __syncthreads();

    int wid = tid >> 6, lane = tid & 63;
    int t = blockIdx.x * 4 + wid;
    float acc[8] = {0.f, 0.f, 0.f, 0.f, 0.f, 0.f, 0.f, 0.f};
    const float* xp = x + (size_t)t * D_DIM + lane;
    for (int c = 0; c < D_DIM / 64; ++c) {
        float xv = xp[c * 64];
#pragma unroll
        for (int e = 0; e < 8; ++e) acc[e] += xv * wgT[e * D_DIM + c * 64 + lane];
    }
#pragma unroll
    for (int e = 0; e < 8; ++e) {
        float v = acc[e];
        for (int o = 32; o; o >>= 1) v += __shfl_xor(v, o);
        acc[e] = v;
    }
    if (lane == 0) {
        float mx = -1e30f;
#pragma unroll
        for (int e = 0; e < 8; ++e) { acc[e] += bg[e]; mx = fmaxf(mx, acc[e]); }
        float p[8], s = 0.f;
#pragma unroll
        for (int e = 0; e < 8; ++e) { p[e] = expf(acc[e] - mx); s += p[e]; }
        int best = 0; float bv = acc[0];
#pragma unroll
        for (int e = 1; e < 8; ++e) if (acc[e] > bv) { bv = acc[e]; best = e; }
        top1[t]  = best;
        score[t] = p[best] / s;
    }
}

// ---------------- deterministic per-expert reduce + BM=256 tile table + cursors ----------------
__global__ void k_meta(const int* __restrict__ top1, const float* __restrict__ score,
                       int* __restrict__ mi, float* __restrict__ mf) {
    int wid = threadIdx.x >> 6, lane = threadIdx.x & 63;
    float s[8] = {0.f, 0.f, 0.f, 0.f, 0.f, 0.f, 0.f, 0.f};
    int   c[8] = {0, 0, 0, 0, 0, 0, 0, 0};
    for (int it = 0; it < T_TOK / 512; ++it) {
        int t = wid * (T_TOK / 8) + it * 64 + lane;
        int e = top1[t]; float sc = score[t];
#pragma unroll
        for (int k = 0; k < 8; ++k) {
            bool m = (e == k);
            s[k] += m ? sc : 0.f;
            c[k] += m ? 1 : 0;
        }
    }
#pragma unroll
    for (int k = 0; k < 8; ++k)
        for (int o = 32; o; o >>= 1) { s[k] += __shfl_down(s[k], o); c[k] += __shfl_down(c[k], o); }
    __shared__ float ss[8][8];
    __shared__ int   cc[8][8];
    if (lane == 0) {
#pragma unroll
        for (int k = 0; k < 8; ++k) { ss[wid][k] = s[k]; cc[wid][k] = c[k]; }
    }
    __syncthreads();
    if (threadIdx.x == 0) {
        int off = 0, ntA = 0;
        for (int e = 0; e < 8; ++e) {
            int   ct = 0; float st = 0.f;
#pragma unroll
            for (int w2 = 0; w2 < 8; ++w2) { ct += cc[w2][e]; st += ss[w2][e]; }
            mi[16 + e] = off;                       // scatter cursor
            mf[e]      = st;
            mf[8 + e]  = (float)T_TOK / (st + EPSV);
            int end = off + ct;
            for (int m = off; m < end; m += 256) {  // BM=256 tiles (expert-sorted order)
                mi[64  + ntA] = e;
                mi[104 + ntA] = m;
                mi[144 + ntA] = end;
                ntA++;
            }
            off = end;
        }
        mi[0] = ntA;
        mi[8] = 0;   // GEMM1 steal cursor
        mi[9] = 0;   // GEMM2 steal cursor
    }
}

// ---------------- scatter tokens to expert-contiguous slots ----------------
__global__ __launch_bounds__(256) void k_scatter(const int* __restrict__ top1,
                                                 const float* __restrict__ score,
                                                 int* __restrict__ mi,
                                                 const float* __restrict__ mf,
                                                 int* __restrict__ perm,
                                                 float* __restrict__ coef) {
    int t = blockIdx.x * 256 + threadIdx.x;
    if (t >= T_TOK) return;
    int e = top1[t];
    int slot = atomicAdd(&mi[16 + e], 1);
    perm[slot] = t;
    coef[slot] = score[t] * mf[8 + e];
}

// ---------------- gather x rows into bf16, slot order ----------------
__global__ __launch_bounds__(256) void k_gatherX(const float* __restrict__ x,
                                                 const int* __restrict__ perm,
                                                 unsigned short* __restrict__ Xg) {
    int i = blockIdx.x * 256 + threadIdx.x;
    int slot = i >> 7, ch = (i & 127) * 8;
    int t = perm[slot];
    const float4* px = (const float4*)(x + (size_t)t * D_DIM + ch);
    float4 a = px[0], b = px[1];
    union { unsigned short u[8]; uint4 v; } o;
    o.u[0] = f2bf(a.x); o.u[1] = f2bf(a.y); o.u[2] = f2bf(a.z); o.u[3] = f2bf(a.w);
    o.u[4] = f2bf(b.x); o.u[5] = f2bf(b.y); o.u[6] = f2bf(b.z); o.u[7] = f2bf(b.w);
    *(uint4*)(Xg + (size_t)slot * D_DIM + ch) = o.v;
}

// ---------------- transpose + cast weights: [E][R][C] f32 -> [E][C][R] bf16 ----------------
__global__ __launch_bounds__(256) void k_transp(const float* __restrict__ W,
                                                unsigned short* __restrict__ Wt,
                                                int R, int C) {
    __shared__ float tile[64][65];
    int e  = blockIdx.z;
    int c0 = blockIdx.x * 64, r0 = blockIdx.y * 64;
    int tr = threadIdx.x >> 6, tc = threadIdx.x & 63;
    const float* Win = W + ((size_t)e * R + r0) * C + c0;
#pragma unroll
    for (int it = 0; it < 16; ++it) {
        int r = it * 4 + tr;
        tile[r][tc] = Win[(size_t)r * C + tc];
    }
    __syncthreads();
    unsigned short* Wo = Wt + ((size_t)e * C + c0) * R + r0;
#pragma unroll
    for (int it = 0; it < 16; ++it) {
        int r = it * 4 + tr;
        Wo[(size_t)r * R + tc] = f2bf(tile[tc][r]);
    }
}

// ====== PERSISTENT grouped GEMM: 256x256 tile, BK=32, 4-buffer / prefetch-distance-3 ======
// Grid 256 (1 block/CU, 128 KB LDS), 8 waves (2M x 4N).  Global-steal queue (R7 style).
// Per K-tile: { VMCNT(8)=2 tiles in flight -> barrier -> stage(kt+3) -> 12x ds_read_b128
//               -> lgkmcnt(0) -> setprio + 32 MFMA }.  Deep counted prefetch gives ~3 kt
// (2-4 us) of L3-latency cover, vs ~0.5 us in the 8-phase variant (R7/R8's stall).
// Queue: q -> (ti = q>>4, sub = q&15), total = nt*16.
//   MODE 0 (H=relu(Xg@W1t), K=1024):      n0 = sub*256,           kOff = 0,          NT=32
//   MODE 1 (out+=coef*(H@W2t), split-K 4): n0 = (sub&3)*256,      kOff = (sub>>2)*1024, NT=32
// Determinism: GEMM1 tiles disjoint; GEMM2 = 4 commutative f32 atomic adds per output.
template <int MODE>
__global__ __launch_bounds__(512, 2) void k_moe_gemm(const unsigned short* __restrict__ A,
                                                     const unsigned short* __restrict__ B,
                                                     void* __restrict__ Cout,
                                                     int* __restrict__ mi,
                                                     const int* __restrict__ perm,
                                                     const float* __restrict__ coef,
                                                     const int KSTRIDE, const int N_TOT) {
    extern __shared__ __align__(16) char lds[];
    __shared__ int sh_t;
    constexpr int NT = 32;
    const int nt    = mi[0];
    const int total = nt * 16;
    int* ctr = &mi[8 + MODE];

    const int tid = threadIdx.x;
    const int w   = tid >> 6, l = tid & 63;
    const int wr  = w >> 2, wc = w & 3;
    const int fr  = l & 15, fq = l >> 4;
    const int gch  = (l & 3) ^ ((l >> 3) & 3);     // inverse-swizzled 16B chunk (R5 pair)
    const int pos16 = (fq ^ ((fr >> 1) & 3)) * 16; // read-side swizzle
    const int rowS = w * 16 + (l >> 2);            // staging row within 128-row half
    const int sdst = w * 1024 + l * 16;            // linear LDS dst (wave-uniform + lane*16)

    for (;;) {
        if (tid == 0) sh_t = atomicAdd(ctr, 1);
        __syncthreads();
        const int q = sh_t;
        if (q >= total) break;

        const int ti  = q >> 4;
        const int sub = q & 15;
        int n0, kOff;
        if (MODE == 0) { n0 = sub << 8;        kOff = 0; }
        else           { n0 = (sub & 3) << 8;  kOff = (sub >> 2) * 1024; }
        const int e    = mi[64 + ti];
        const int m0   = mi[104 + ti];
        const int mend = mi[144 + ti];
        const unsigned short* Bexp = B + (size_t)e * N_TOT * KSTRIDE;

        // per-thread staging sources (elements): row rG, k-offset kOff + kt*32, chunk gch
        const unsigned short* aS[2];
        const unsigned short* bS[2];
#pragma unroll
        for (int s = 0; s < 2; ++s) {
            int rT = s * 128 + rowS;
            int rG = m0 + rT; if (rG > T_TOK - 1) rG = T_TOK - 1;   // clamp tail rows
            aS[s] = A + (size_t)rG * KSTRIDE + kOff + gch * 8;
            bS[s] = Bexp + (size_t)(n0 + rT) * KSTRIDE + kOff + gch * 8;
        }

        auto stage = [&](int kt) {
            if (kt < NT) {
                char* bb = lds + (kt & 3) * 32768;
                const int ko = kt * 32;
                __builtin_amdgcn_global_load_lds((gvoid_t*)(aS[0] + ko), (lvoid_t*)(bb + sdst),          16, 0, 0);
                __builtin_amdgcn_global_load_lds((gvoid_t*)(aS[1] + ko), (lvoid_t*)(bb + 8192 + sdst),   16, 0, 0);
                __builtin_amdgcn_global_load_lds((gvoid_t*)(bS[0] + ko), (lvoid_t*)(bb + 16384 + sdst),  16, 0, 0);
                __builtin_amdgcn_global_load_lds((gvoid_t*)(bS[1] + ko), (lvoid_t*)(bb + 24576 + sdst),  16, 0, 0);
            }
        };

        f32x4 acc[8][4];
#pragma unroll
        for (int m = 0; m < 8; ++m)
#pragma unroll
            for (int n = 0; n < 4; ++n) acc[m][n] = (f32x4){0.f, 0.f, 0.f, 0.f};

        // prologue: prefetch K-tiles 0,1,2 (12 loads/thread in flight)
        stage(0); stage(1); stage(2);

        for (int kt = 0; kt < NT; ++kt) {
            // counted wait: newest 8 loads = tiles kt+1,kt+2 (still in flight); kt complete
            if (kt < NT - 2)       { VMCNT(8); }
            else if (kt == NT - 2) { VMCNT(4); }
            else                   { VMCNT(0); }
            SCHEDB();
            __builtin_amdgcn_s_barrier();      // all waves' kt loads have landed in LDS
            stage(kt + 3);                     // refill buffer (kt-1)&3 (consumed last iter)

            const char* bb = lds + (kt & 3) * 32768;
            bf16x8 af[8], bfr[4];
#pragma unroll
            for (int n = 0; n < 4; ++n)
                bfr[n] = *(const bf16x8*)(bb + 16384 + (wc * 64 + n * 16 + fr) * 64 + pos16);
#pragma unroll
            for (int m = 0; m < 8; ++m)
                af[m] = *(const bf16x8*)(bb + (wr * 128 + m * 16 + fr) * 64 + pos16);
            asm volatile("s_waitcnt lgkmcnt(0)" ::: "memory");
            SCHEDB();
            __builtin_amdgcn_s_setprio(1);
#pragma unroll
            for (int m = 0; m < 8; ++m)
#pragma unroll
                for (int n = 0; n < 4; ++n)
                    acc[m][n] = __builtin_amdgcn_mfma_f32_16x16x32_bf16(af[m], bfr[n], acc[m][n], 0, 0, 0);
            __builtin_amdgcn_s_setprio(0);
            SCHEDB();
        }

        // ---- epilogue (no LDS use; overlaps next tile's prologue staging) ----
        if (MODE == 0) {
            unsigned short* H = (unsigned short*)Cout;
#pragma unroll
            for (int m = 0; m < 8; ++m) {
                int rb = m0 + wr * 128 + m * 16 + fq * 4;
#pragma unroll
                for (int r = 0; r < 4; ++r) {
                    int row = rb + r;
                    if (row < mend) {
#pragma unroll
                        for (int n = 0; n < 4; ++n) {
                            int col = n0 + wc * 64 + n * 16 + fr;
                            float v = fmaxf(acc[m][n][r], 0.f);
                            H[(size_t)row * N_TOT + col] = f2bf(v);
                        }
                    }
                }
            }
        } else {
            float* O = (float*)Cout;
#pragma unroll
            for (int m = 0; m < 8; ++m) {
                int rb = m0 + wr * 128 + m * 16 + fq * 4;
#pragma unroll
                for (int r = 0; r < 4; ++r) {
                    int row = rb + r;
                    if (row < mend) {
                        int   tkn = perm[row];
                        float cf  = coef[row];
#pragma unroll
                        for (int n = 0; n < 4; ++n) {
                            int col = n0 + wc * 64 + n * 16 + fr;
                            unsafeAtomicAdd(&O[(size_t)tkn * N_TOT + col], cf * acc[m][n][r]);
                        }
                    }
                }
            }
        }
    }
}

extern "C" void kernel_launch(void* const* d_in, const int* in_sizes, int n_in,
                              void* d_out, int out_size, void* d_ws, size_t ws_size,
                              hipStream_t stream) {
    const float* x  = (const float*)d_in[0];
    const float* Wg = (const float*)d_in[1];
    const float* bg = (const float*)d_in[2];
    const float* W1 = (const float*)d_in[3];
    const float* W2 = (const float*)d_in[4];

    char* ws = (char*)d_ws;
    int*   mi    = (int*)ws;
    float* mf    = (float*)(ws + 2048);
    int*   top1  = (int*)(ws + 4096);
    float* score = (float*)(ws + 36864);
    int*   perm  = (int*)(ws + 69632);
    float* coef  = (float*)(ws + 102400);
    unsigned short* Xg = (unsigned short*)(ws + 135168);     // 8192 x 1024 bf16
    unsigned short* H  = (unsigned short*)(ws + 16912384);   // 8192 x 4096 bf16
    unsigned short* Wt = (unsigned short*)(ws + 84021248);   // 8 x 4096 x 1024 bf16 (shared)

    hipFuncSetAttribute((const void*)&k_moe_gemm<0>,
                        hipFuncAttributeMaxDynamicSharedMemorySize, 131072);
    hipFuncSetAttribute((const void*)&k_moe_gemm<1>,
                        hipFuncAttributeMaxDynamicSharedMemorySize, 131072);

    // zero d_out: GEMM2 combines split-K quarters with commutative f32 atomic adds
    hipMemsetAsync(d_out, 0, (size_t)out_size * sizeof(float), stream);

    k_gate<<<dim3(T_TOK / 4), dim3(256), 0, stream>>>(x, Wg, bg, top1, score);
    k_meta<<<dim3(1), dim3(512), 0, stream>>>(top1, score, mi, mf);
    k_scatter<<<dim3(T_TOK / 256), dim3(256), 0, stream>>>(top1, score, mi, mf, perm, coef);
    k_gatherX<<<dim3(T_TOK * 128 / 256), dim3(256), 0, stream>>>(x, perm, Xg);

    // W1: [8][1024][4096] f32 -> Wt [8][4096][1024] bf16
    k_transp<<<dim3(N_INNER / 64, D_DIM / 64, NEXP), dim3(256), 0, stream>>>(W1, Wt, D_DIM, N_INNER);
    // H = relu(Xg @ W1t): persistent global-steal, nt*16 tiles, NT=32 (BK=32)
    k_moe_gemm<0><<<dim3(256), dim3(512), 131072, stream>>>(
        Xg, Wt, (void*)H, mi, perm, coef, D_DIM, N_INNER);
    // W2: [8][4096][1024] f32 -> Wt [8][1024][4096] bf16
    k_transp<<<dim3(D_DIM / 64, N_INNER / 64, NEXP), dim3(256), 0, stream>>>(W2, Wt, N_INNER, D_DIM);
    // out += coef * (H @ W2t): persistent global-steal, split-K 4, nt*16 tiles, NT=32
    k_moe_gemm<1><<<dim3(256), dim3(512), 131072, stream>>>(
        H, Wt, d_out, mi, perm, coef, N_INNER, D_DIM);
}